// Round 3
// baseline (137.154 us; speedup 1.0000x reference)
//
#include <hip/hip_runtime.h>
#include <hip/hip_bf16.h>
#include <stdint.h>

#define NN 2048
#define LOG2NN 11
#define GK 2048
#define GNC 2048

typedef __bf16 bf16x8 __attribute__((ext_vector_type(8)));
typedef float f32x4 __attribute__((ext_vector_type(4)));

// round-to-nearest-even f32 -> bf16 bits
__device__ __forceinline__ ushort f2bf(float f) {
  uint32_t x = __float_as_uint(f);
  uint32_t r = (x + 0x7fffu + ((x >> 16) & 1u)) >> 16;
  return (ushort)r;
}

// ---------------------------------------------------------------- init
__global__ void init_kernel(int* __restrict__ hist, float* __restrict__ uW,
                            int* __restrict__ ecnt) {
  int i = blockIdx.x * blockDim.x + threadIdx.x;  // 2048 threads
  hist[i] = 0;
  uW[i] = 0.f;
  if (i == 0) *ecnt = 0;
}

// ---------------------------------------------------------------- softmax (per-row)
__device__ __forceinline__ int lower_bound32(const int* __restrict__ a, int n, int v) {
  int lo = 0, hi = n;
  while (lo < hi) {
    int mid = (lo + hi) >> 1;
    if (a[mid] < v) lo = mid + 1; else hi = mid;
  }
  return lo;
}

// one wave per row r: segmented softmax over sorted edge list; store per-edge
// probabilities to vals[], diagonal value to diag[r], empty flag.
__global__ void softmax_kernel(const int* __restrict__ idx, const float* __restrict__ e,
                               int nnz, float* __restrict__ vals,
                               float* __restrict__ diag, int* __restrict__ empty,
                               int* __restrict__ ecnt) {
  int r = blockIdx.x;
  int lane = threadIdx.x;
  int lo = lower_bound32(idx, nnz, r << LOG2NN);
  int hi = lower_bound32(idx, nnz, (r + 1) << LOG2NN);
  if (hi <= lo) {  // empty row: softmax of all-equal NEG -> uniform 1/NN
    if (lane == 0) { diag[r] = 1.0f / NN; empty[r] = 1; atomicAdd(ecnt, 1); }
    return;
  }
  float m = -3.0e38f;
  for (int j = lo + lane; j < hi; j += 64) m = fmaxf(m, e[j]);
#pragma unroll
  for (int s = 32; s >= 1; s >>= 1) m = fmaxf(m, __shfl_xor(m, s));
  float sum = 0.f;
  for (int j = lo + lane; j < hi; j += 64) sum += expf(e[j] - m);
#pragma unroll
  for (int s = 32; s >= 1; s >>= 1) sum += __shfl_xor(sum, s);
  float inv = 1.0f / sum;
  float dv = 0.f;
  for (int j = lo + lane; j < hi; j += 64) {
    float v = expf(e[j] - m) * inv;
    vals[j] = v;
    if ((idx[j] & (NN - 1)) == r) dv = v;  // diagonal
  }
#pragma unroll
  for (int s = 32; s >= 1; s >>= 1) dv += __shfl_xor(dv, s);
  if (lane == 0) { diag[r] = dv; empty[r] = 0; }
}

// ---------------------------------------------------------------- bucket by column
__global__ void hist_kernel(const int* __restrict__ idx, int nnz, int* __restrict__ hist) {
  int j = blockIdx.x * blockDim.x + threadIdx.x;
  if (j >= nnz) return;
  int f = idx[j];
  int c = f & (NN - 1), r = f >> LOG2NN;
  if (c != r) atomicAdd(&hist[c], 1);
}

// exclusive prefix sum of hist[2048] -> base, cursor. 1 block x 1024 threads.
__global__ void scan_kernel(const int* __restrict__ hist, int* __restrict__ base,
                            int* __restrict__ cursor) {
  __shared__ int s[1024];
  int t = threadIdx.x;
  int h0 = hist[2 * t], h1 = hist[2 * t + 1];
  s[t] = h0 + h1;
  __syncthreads();
#pragma unroll
  for (int off = 1; off < 1024; off <<= 1) {
    int v = (t >= off) ? s[t - off] : 0;
    __syncthreads();
    s[t] += v;
    __syncthreads();
  }
  int excl = s[t] - (h0 + h1);
  base[2 * t] = excl;           cursor[2 * t] = excl;
  base[2 * t + 1] = excl + h0;  cursor[2 * t + 1] = excl + h0;
}

__global__ void scatter_kernel(const int* __restrict__ idx, const float* __restrict__ vals,
                               int nnz, int* __restrict__ cursor,
                               int* __restrict__ ek, float* __restrict__ ev) {
  int j = blockIdx.x * blockDim.x + threadIdx.x;
  if (j >= nnz) return;
  int f = idx[j];
  int c = f & (NN - 1), r = f >> LOG2NN;
  if (c != r) {
    int p = atomicAdd(&cursor[c], 1);
    ek[p] = r;
    ev[p] = vals[j];
  }
}

// uW[p] = (1/NN) * sum_{empty k} W2[p,k]  (dead unless an empty row exists)
__global__ void uw_kernel(const float* __restrict__ W2, const int* __restrict__ empty,
                          const int* __restrict__ ecnt, float* __restrict__ uW) {
  if (*ecnt == 0) return;
  int p = blockIdx.x * blockDim.x + threadIdx.x;
  if (p >= NN) return;
  float s = 0.f;
  for (int k = 0; k < NN; ++k)
    if (empty[k]) s += W2[(size_t)p * NN + k];
  uW[p] = s * (1.0f / NN);
}

// ---------------------------------------------------------------- transpose f32 -> bf16^T
// out[c][r] = (bf16) in[r][c].  64x64 tiles, 256 threads.
__global__ __launch_bounds__(256) void transpose_bf16_kernel(
    const float* __restrict__ W1, const float* __restrict__ W2,
    ushort* __restrict__ W1T, ushort* __restrict__ W2T) {
  __shared__ float tile[64][65];
  const float* in = blockIdx.z ? W2 : W1;
  ushort* out = blockIdx.z ? W2T : W1T;
  const int r0 = blockIdx.y * 64, c0 = blockIdx.x * 64;
  const int t = threadIdx.x;
  const int tx = t & 15, ty = t >> 4;
#pragma unroll
  for (int i = 0; i < 4; ++i) {
    int r = i * 16 + ty;
    float4 v = *reinterpret_cast<const float4*>(&in[(size_t)(r0 + r) * NN + c0 + tx * 4]);
    tile[r][tx * 4 + 0] = v.x;
    tile[r][tx * 4 + 1] = v.y;
    tile[r][tx * 4 + 2] = v.z;
    tile[r][tx * 4 + 3] = v.w;
  }
  __syncthreads();
#pragma unroll
  for (int i = 0; i < 4; ++i) {
    int oc = i * 16 + ty;  // output row = original col
    ushort4 o;
    o.x = f2bf(tile[tx * 4 + 0][oc]);
    o.y = f2bf(tile[tx * 4 + 1][oc]);
    o.z = f2bf(tile[tx * 4 + 2][oc]);
    o.w = f2bf(tile[tx * 4 + 3][oc]);
    *reinterpret_cast<ushort4*>(&out[(size_t)(c0 + oc) * NN + r0 + tx * 4]) = o;
  }
}

// ---------------------------------------------------------------- f32 -> bf16 (vectorized)
__global__ void f32_to_bf16_kernel(const float* __restrict__ in, ushort* __restrict__ out,
                                   int n8) {
  int i = blockIdx.x * blockDim.x + threadIdx.x;
  if (i >= n8) return;
  const float4* in4 = reinterpret_cast<const float4*>(in);
  float4 a = in4[2 * i];
  float4 b = in4[2 * i + 1];
  uint4 o;
  o.x = (uint32_t)f2bf(a.x) | ((uint32_t)f2bf(a.y) << 16);
  o.y = (uint32_t)f2bf(a.z) | ((uint32_t)f2bf(a.w) << 16);
  o.z = (uint32_t)f2bf(b.x) | ((uint32_t)f2bf(b.y) << 16);
  o.w = (uint32_t)f2bf(b.z) | ((uint32_t)f2bf(b.w) << 16);
  reinterpret_cast<uint4*>(out)[i] = o;
}

// ---------------------------------------------------------------- SpMM: WfT rows
// One wave per output row n. WT holds W1^T on entry; wave n reads WT[n,:] (diag
// term) then overwrites WT[n,:] with Wfused^T row n (row-exclusive in-place).
//   WfT[n,p] = sum_{edges(k,n)} v * W2T[k,p] + diag[n]*W1T[n,p] + uW[p]
//              - empty[n]*W2T[n,p]/NN
__global__ __launch_bounds__(256) void spmm_kernel(
    const int* __restrict__ ek, const float* __restrict__ ev,
    const int* __restrict__ base, const int* __restrict__ hist,
    const ushort* __restrict__ W2T,
    const float* __restrict__ diag, const int* __restrict__ empty,
    const float* __restrict__ uW, ushort* WT) {
  const int w = threadIdx.x >> 6, lane = threadIdx.x & 63;
  const int n = blockIdx.x * 4 + w;
  const int start = base[n], cnt = hist[n];
  float acc[4][8];
#pragma unroll
  for (int g = 0; g < 4; ++g) {
    float4 u0 = *reinterpret_cast<const float4*>(&uW[g * 512 + lane * 8]);
    float4 u1 = *reinterpret_cast<const float4*>(&uW[g * 512 + lane * 8 + 4]);
    acc[g][0] = u0.x; acc[g][1] = u0.y; acc[g][2] = u0.z; acc[g][3] = u0.w;
    acc[g][4] = u1.x; acc[g][5] = u1.y; acc[g][6] = u1.z; acc[g][7] = u1.w;
  }
  // diag term first (reads WT row n before it is overwritten below)
  float d = diag[n];
  if (d != 0.f) {
#pragma unroll
    for (int g = 0; g < 4; ++g) {
      bf16x8 wd = *reinterpret_cast<const bf16x8*>(&WT[(size_t)n * NN + g * 512 + lane * 8]);
#pragma unroll
      for (int j = 0; j < 8; ++j) acc[g][j] += d * (float)wd[j];
    }
  }
  int i = 0;
  for (; i + 2 <= cnt; i += 2) {
    int k0 = ek[start + i], k1 = ek[start + i + 1];
    float v0 = ev[start + i], v1 = ev[start + i + 1];
    bf16x8 w0[4], w1[4];
#pragma unroll
    for (int g = 0; g < 4; ++g)
      w0[g] = *reinterpret_cast<const bf16x8*>(&W2T[(size_t)k0 * NN + g * 512 + lane * 8]);
#pragma unroll
    for (int g = 0; g < 4; ++g)
      w1[g] = *reinterpret_cast<const bf16x8*>(&W2T[(size_t)k1 * NN + g * 512 + lane * 8]);
#pragma unroll
    for (int g = 0; g < 4; ++g)
#pragma unroll
      for (int j = 0; j < 8; ++j)
        acc[g][j] += v0 * (float)w0[g][j] + v1 * (float)w1[g][j];
  }
  if (i < cnt) {
    int k0 = ek[start + i];
    float v0 = ev[start + i];
#pragma unroll
    for (int g = 0; g < 4; ++g) {
      bf16x8 w0 = *reinterpret_cast<const bf16x8*>(&W2T[(size_t)k0 * NN + g * 512 + lane * 8]);
#pragma unroll
      for (int j = 0; j < 8; ++j) acc[g][j] += v0 * (float)w0[j];
    }
  }
  if (empty[n]) {
#pragma unroll
    for (int g = 0; g < 4; ++g) {
      bf16x8 we = *reinterpret_cast<const bf16x8*>(&W2T[(size_t)n * NN + g * 512 + lane * 8]);
#pragma unroll
      for (int j = 0; j < 8; ++j) acc[g][j] -= (1.0f / NN) * (float)we[j];
    }
  }
#pragma unroll
  for (int g = 0; g < 4; ++g) {
    uint4 o;
    o.x = (uint32_t)f2bf(acc[g][0]) | ((uint32_t)f2bf(acc[g][1]) << 16);
    o.y = (uint32_t)f2bf(acc[g][2]) | ((uint32_t)f2bf(acc[g][3]) << 16);
    o.z = (uint32_t)f2bf(acc[g][4]) | ((uint32_t)f2bf(acc[g][5]) << 16);
    o.w = (uint32_t)f2bf(acc[g][6]) | ((uint32_t)f2bf(acc[g][7]) << 16);
    *reinterpret_cast<uint4*>(&WT[(size_t)n * NN + g * 512 + lane * 8]) = o;
  }
}

// ---------------------------------------------------------------- bf16 bt-GEMM (m97 structure)
// C[row, col] = sum_k A[row, k] * Bt[col, k]; 128x128 tile, 4 waves, BK=32.
__device__ __forceinline__ void gload_lds16(const ushort* g, char* l) {
  __builtin_amdgcn_global_load_lds(
      (__attribute__((address_space(1))) uint32_t*)(uintptr_t)g,
      (__attribute__((address_space(3))) uint32_t*)l, 16, 0, 0);
}

__global__ __launch_bounds__(256)
void gemm_bt_kernel(const ushort* __restrict__ A, const ushort* __restrict__ Bt,
                    float* __restrict__ Cf) {
  __shared__ ushort As[128 * 32];
  __shared__ ushort Bs[128 * 32];
  const int t = threadIdx.x;
  const int wid = t >> 6;
  const int lane = t & 63;
  const int m0 = blockIdx.y * 128;
  const int n0 = blockIdx.x * 128;
  const int wm = wid >> 1, wn = wid & 1;

  f32x4 acc[4][4] = {};

  const ushort* Ag0 = A + (size_t)(m0 + (t >> 2)) * GK + (t & 3) * 8;
  const ushort* Ag1 = Ag0 + (size_t)64 * GK;
  const ushort* Bg0 = Bt + (size_t)(n0 + (t >> 2)) * GK + (t & 3) * 8;
  const ushort* Bg1 = Bg0 + (size_t)64 * GK;
  char* AsW = (char*)As + wid * 1024;
  char* BsW = (char*)Bs + wid * 1024;

  const int fr = lane & 15, fg = lane >> 4;
  const ushort* ArdA = As + (size_t)(wm * 64 + fr) * 32 + fg * 8;
  const ushort* ArdB = Bs + (size_t)(wn * 64 + fr) * 32 + fg * 8;

  for (int kt = 0; kt < GK; kt += 32) {
    gload_lds16(Ag0 + kt, AsW);
    gload_lds16(Ag1 + kt, AsW + 4096);
    gload_lds16(Bg0 + kt, BsW);
    gload_lds16(Bg1 + kt, BsW + 4096);
    __syncthreads();
    bf16x8 af[4], bb[4];
#pragma unroll
    for (int i = 0; i < 4; ++i) af[i] = *reinterpret_cast<const bf16x8*>(ArdA + i * 16 * 32);
#pragma unroll
    for (int i = 0; i < 4; ++i) bb[i] = *reinterpret_cast<const bf16x8*>(ArdB + i * 16 * 32);
#pragma unroll
    for (int i = 0; i < 4; ++i)
#pragma unroll
      for (int j = 0; j < 4; ++j)
        acc[i][j] = __builtin_amdgcn_mfma_f32_16x16x32_bf16(af[i], bb[j], acc[i][j], 0, 0, 0);
    __syncthreads();
  }

  const int cr = lane >> 4, cc = lane & 15;
#pragma unroll
  for (int i = 0; i < 4; ++i)
#pragma unroll
    for (int j = 0; j < 4; ++j)
#pragma unroll
      for (int q = 0; q < 4; ++q) {
        int grow = m0 + wm * 64 + i * 16 + cr * 4 + q;
        int gcol = n0 + wn * 64 + j * 16 + cc;
        Cf[(size_t)grow * GNC + gcol] = acc[i][j][q];
      }
}

// ---------------------------------------------------------------- launch
extern "C" void kernel_launch(void* const* d_in, const int* in_sizes, int n_in,
                              void* d_out, int out_size, void* d_ws, size_t ws_size,
                              hipStream_t stream) {
  const float* x   = (const float*)d_in[0];  // [8,512,2048] -> [4096][2048]
  const float* W1  = (const float*)d_in[1];  // [2048][2048]
  const float* W2  = (const float*)d_in[2];  // [2048][2048]
  const float* e   = (const float*)d_in[3];  // [nnz]
  const int*   eix = (const int*)d_in[4];    // [nnz] sorted flat indices
  const int nnz = in_sizes[3];
  float* out = (float*)d_out;                // [4096][2048] fp32

  // ws layout: 34.39 MB total (round-1's 41.97 MB footprint passed post-timing
  // validation, so stay strictly below it; WfT aliases W1T's slot).
  char* w = (char*)d_ws;
  ushort* W2T  = (ushort*)w; w += (size_t)NN * NN * 2;    // 8.4 MB  W2^T bf16 [k][p]
  ushort* WT   = (ushort*)w; w += (size_t)NN * NN * 2;    // 8.4 MB  W1^T then Wfused^T [n][p]
  ushort* xb   = (ushort*)w; w += (size_t)4096 * NN * 2;  // 16.8 MB x bf16 [m][p]
  float*  vals = (float*)w;  w += (size_t)nnz * 4;
  int*    ek   = (int*)w;    w += (size_t)nnz * 4;
  float*  ev   = (float*)w;  w += (size_t)nnz * 4;
  int*    hist = (int*)w;    w += NN * 4;
  int*    base = (int*)w;    w += NN * 4;
  int*    curs = (int*)w;    w += NN * 4;
  float*  diag = (float*)w;  w += NN * 4;
  int*    empt = (int*)w;    w += NN * 4;
  float*  uW   = (float*)w;  w += NN * 4;
  int*    ecnt = (int*)w;    w += 256;

  init_kernel<<<dim3(8), dim3(256), 0, stream>>>(hist, uW, ecnt);
  softmax_kernel<<<dim3(NN), dim3(64), 0, stream>>>(eix, e, nnz, vals, diag, empt, ecnt);
  hist_kernel<<<dim3((nnz + 255) / 256), dim3(256), 0, stream>>>(eix, nnz, hist);
  scan_kernel<<<dim3(1), dim3(1024), 0, stream>>>(hist, base, curs);
  scatter_kernel<<<dim3((nnz + 255) / 256), dim3(256), 0, stream>>>(eix, vals, nnz, curs, ek, ev);
  uw_kernel<<<dim3(8), dim3(256), 0, stream>>>(W2, empt, ecnt, uW);
  transpose_bf16_kernel<<<dim3(32, 32, 2), dim3(256), 0, stream>>>(W1, W2, WT, W2T);
  f32_to_bf16_kernel<<<dim3(4096), dim3(256), 0, stream>>>(x, xb, 4096 * NN / 8);
  spmm_kernel<<<dim3(512), dim3(256), 0, stream>>>(ek, ev, base, hist, W2T,
                                                   diag, empt, uW, WT);
  gemm_bt_kernel<<<dim3(16, 32), dim3(256), 0, stream>>>(xb, WT, out);
}

// Round 4
// 124.999 us; speedup vs baseline: 1.0972x; 1.0972x over previous
//
#include <hip/hip_runtime.h>
#include <hip/hip_bf16.h>
#include <stdint.h>

#define NN 2048
#define LOG2NN 11
#define GK 2048
#define GNC 2048

typedef __bf16 bf16x8 __attribute__((ext_vector_type(8)));
typedef float f32x4 __attribute__((ext_vector_type(4)));

// round-to-nearest-even f32 -> bf16 bits
__device__ __forceinline__ ushort f2bf(float f) {
  uint32_t x = __float_as_uint(f);
  uint32_t r = (x + 0x7fffu + ((x >> 16) & 1u)) >> 16;
  return (ushort)r;
}

// ---------------------------------------------------------------- prep (fused)
// blocks [0,2048): transpose W1/W2 f32 -> bf16^T (64x64 tiles)
// blocks [2048,6144): x f32 -> bf16 (8 elems/thread)
// block 6144: zero hist/uW/ecnt
__global__ __launch_bounds__(256) void prep_kernel(
    const float* __restrict__ W1, const float* __restrict__ W2,
    ushort* __restrict__ WT, ushort* __restrict__ W2T,
    const float* __restrict__ x, ushort* __restrict__ xb,
    int* __restrict__ hist, float* __restrict__ uW, int* __restrict__ ecnt) {
  __shared__ float tile[64][65];
  const int bid = blockIdx.x;
  const int t = threadIdx.x;
  if (bid < 2048) {  // transpose: out[c][r] = (bf16) in[r][c]
    const int m = bid >> 10;            // 0 = W1, 1 = W2
    const int rem = bid & 1023;
    const int r0 = (rem >> 5) * 64, c0 = (rem & 31) * 64;
    const float* in = m ? W2 : W1;
    ushort* out = m ? W2T : WT;
    const int tx = t & 15, ty = t >> 4;
#pragma unroll
    for (int i = 0; i < 4; ++i) {
      int r = i * 16 + ty;
      float4 v = *reinterpret_cast<const float4*>(&in[(size_t)(r0 + r) * NN + c0 + tx * 4]);
      tile[r][tx * 4 + 0] = v.x;
      tile[r][tx * 4 + 1] = v.y;
      tile[r][tx * 4 + 2] = v.z;
      tile[r][tx * 4 + 3] = v.w;
    }
    __syncthreads();
#pragma unroll
    for (int i = 0; i < 4; ++i) {
      int oc = i * 16 + ty;  // output row = original col
      ushort4 o;
      o.x = f2bf(tile[tx * 4 + 0][oc]);
      o.y = f2bf(tile[tx * 4 + 1][oc]);
      o.z = f2bf(tile[tx * 4 + 2][oc]);
      o.w = f2bf(tile[tx * 4 + 3][oc]);
      *reinterpret_cast<ushort4*>(&out[(size_t)(c0 + oc) * NN + r0 + tx * 4]) = o;
    }
  } else if (bid < 6144) {  // x f32 -> bf16
    int i = (bid - 2048) * 256 + t;  // 8 floats each
    const float4* in4 = reinterpret_cast<const float4*>(x);
    float4 a = in4[2 * i];
    float4 b = in4[2 * i + 1];
    uint4 o;
    o.x = (uint32_t)f2bf(a.x) | ((uint32_t)f2bf(a.y) << 16);
    o.y = (uint32_t)f2bf(a.z) | ((uint32_t)f2bf(a.w) << 16);
    o.z = (uint32_t)f2bf(b.x) | ((uint32_t)f2bf(b.y) << 16);
    o.w = (uint32_t)f2bf(b.z) | ((uint32_t)f2bf(b.w) << 16);
    reinterpret_cast<uint4*>(xb)[i] = o;
  } else {  // init
#pragma unroll
    for (int j = 0; j < 8; ++j) {
      hist[t * 8 + j] = 0;
      uW[t * 8 + j] = 0.f;
    }
    if (t == 0) *ecnt = 0;
  }
}

// ---------------------------------------------------------------- softmax + hist (fused)
__device__ __forceinline__ int lower_bound32(const int* __restrict__ a, int n, int v) {
  int lo = 0, hi = n;
  while (lo < hi) {
    int mid = (lo + hi) >> 1;
    if (a[mid] < v) lo = mid + 1; else hi = mid;
  }
  return lo;
}

// wave w of block b handles row r = b*4+w: segmented softmax over the sorted
// edge list; per-edge probs -> vals[], diag, empty flag, and hist[c] atomics.
__global__ __launch_bounds__(256) void softmax_hist_kernel(
    const int* __restrict__ idx, const float* __restrict__ e, int nnz,
    float* __restrict__ vals, float* __restrict__ diag, int* __restrict__ empty,
    int* __restrict__ ecnt, int* __restrict__ hist) {
  const int w = threadIdx.x >> 6, lane = threadIdx.x & 63;
  const int r = blockIdx.x * 4 + w;
  int lo = lower_bound32(idx, nnz, r << LOG2NN);
  int hi = lower_bound32(idx, nnz, (r + 1) << LOG2NN);
  if (hi <= lo) {  // empty row: softmax of all-equal NEG -> uniform 1/NN
    if (lane == 0) { diag[r] = 1.0f / NN; empty[r] = 1; atomicAdd(ecnt, 1); }
    return;
  }
  float m = -3.0e38f;
  for (int j = lo + lane; j < hi; j += 64) m = fmaxf(m, e[j]);
#pragma unroll
  for (int s = 32; s >= 1; s >>= 1) m = fmaxf(m, __shfl_xor(m, s));
  float sum = 0.f;
  for (int j = lo + lane; j < hi; j += 64) sum += expf(e[j] - m);
#pragma unroll
  for (int s = 32; s >= 1; s >>= 1) sum += __shfl_xor(sum, s);
  float inv = 1.0f / sum;
  float dv = 0.f;
  for (int j = lo + lane; j < hi; j += 64) {
    float v = expf(e[j] - m) * inv;
    vals[j] = v;
    int c = idx[j] & (NN - 1);
    if (c == r) dv = v;
    else atomicAdd(&hist[c], 1);
  }
#pragma unroll
  for (int s = 32; s >= 1; s >>= 1) dv += __shfl_xor(dv, s);
  if (lane == 0) { diag[r] = dv; empty[r] = 0; }
}

// ---------------------------------------------------------------- scan + uw (fused)
// block 0, lanes 0-63: exclusive prefix sum of hist[2048] (32 elems/lane +
// wave shfl-scan). blocks 1..8: uW (dead unless an empty row exists).
__global__ __launch_bounds__(256) void scan_uw_kernel(
    const int* __restrict__ hist, int* __restrict__ base, int* __restrict__ cursor,
    const float* __restrict__ W2, const int* __restrict__ empty,
    const int* __restrict__ ecnt, float* __restrict__ uW) {
  if (blockIdx.x == 0) {
    const int l = threadIdx.x;
    if (l >= 64) return;
    int vals[32], pre[32];
    int run = 0;
#pragma unroll
    for (int j = 0; j < 32; ++j) {
      vals[j] = hist[l * 32 + j];
      pre[j] = run;
      run += vals[j];
    }
    int tot = run, inc = run;
#pragma unroll
    for (int s = 1; s < 64; s <<= 1) {
      int o = __shfl_up(inc, s);
      if (l >= s) inc += o;
    }
    int excl = inc - tot;
#pragma unroll
    for (int j = 0; j < 32; ++j) {
      int b = excl + pre[j];
      base[l * 32 + j] = b;
      cursor[l * 32 + j] = b;
    }
  } else {
    if (*ecnt == 0) return;
    int p = (blockIdx.x - 1) * 256 + threadIdx.x;
    float s = 0.f;
    for (int k = 0; k < NN; ++k)
      if (empty[k]) s += W2[(size_t)p * NN + k];
    uW[p] = s * (1.0f / NN);
  }
}

// ---------------------------------------------------------------- scatter by column
__global__ void scatter_kernel(const int* __restrict__ idx, const float* __restrict__ vals,
                               int nnz, int* __restrict__ cursor,
                               int* __restrict__ ek, float* __restrict__ ev) {
  int j = blockIdx.x * blockDim.x + threadIdx.x;
  if (j >= nnz) return;
  int f = idx[j];
  int c = f & (NN - 1), r = f >> LOG2NN;
  if (c != r) {
    int p = atomicAdd(&cursor[c], 1);
    ek[p] = r;
    ev[p] = vals[j];
  }
}

// ---------------------------------------------------------------- SpMM: WfT rows
// 4 waves/block; wave handles (row n, p-half h): 1024 cols, 16/lane.
// WT holds W1^T on entry; wave reads WT[n, half] (diag term) then overwrites
// the same range with Wfused^T (region-exclusive in-place).
//   WfT[n,p] = sum_{edges(k,n)} v * W2T[k,p] + diag[n]*W1T[n,p] + uW[p]
//              - empty[n]*W2T[n,p]/NN
__global__ __launch_bounds__(256) void spmm_kernel(
    const int* __restrict__ ek, const float* __restrict__ ev,
    const int* __restrict__ base, const int* __restrict__ hist,
    const ushort* __restrict__ W2T,
    const float* __restrict__ diag, const int* __restrict__ empty,
    const float* __restrict__ uW, ushort* WT) {
  const int w = threadIdx.x >> 6, lane = threadIdx.x & 63;
  const int n = blockIdx.x * 2 + (w >> 1);
  const int c0 = (w & 1) * 1024 + lane * 16;  // groups at c0, c0+8
  const int start = base[n], cnt = hist[n];
  float acc[2][8];
#pragma unroll
  for (int g = 0; g < 2; ++g) {
    float4 u0 = *reinterpret_cast<const float4*>(&uW[c0 + g * 8]);
    float4 u1 = *reinterpret_cast<const float4*>(&uW[c0 + g * 8 + 4]);
    acc[g][0] = u0.x; acc[g][1] = u0.y; acc[g][2] = u0.z; acc[g][3] = u0.w;
    acc[g][4] = u1.x; acc[g][5] = u1.y; acc[g][6] = u1.z; acc[g][7] = u1.w;
  }
  // diag term first (reads WT range before overwriting it below)
  float d = diag[n];
  if (d != 0.f) {
#pragma unroll
    for (int g = 0; g < 2; ++g) {
      bf16x8 wd = *reinterpret_cast<const bf16x8*>(&WT[(size_t)n * NN + c0 + g * 8]);
#pragma unroll
      for (int j = 0; j < 8; ++j) acc[g][j] += d * (float)wd[j];
    }
  }
  int i = 0;
  for (; i + 4 <= cnt; i += 4) {
    int k[4];
    float v[4];
    bf16x8 wv[4][2];
#pragma unroll
    for (int e2 = 0; e2 < 4; ++e2) {
      k[e2] = ek[start + i + e2];
      v[e2] = ev[start + i + e2];
    }
#pragma unroll
    for (int e2 = 0; e2 < 4; ++e2)
#pragma unroll
      for (int g = 0; g < 2; ++g)
        wv[e2][g] = *reinterpret_cast<const bf16x8*>(&W2T[(size_t)k[e2] * NN + c0 + g * 8]);
#pragma unroll
    for (int e2 = 0; e2 < 4; ++e2)
#pragma unroll
      for (int g = 0; g < 2; ++g)
#pragma unroll
        for (int j = 0; j < 8; ++j)
          acc[g][j] += v[e2] * (float)wv[e2][g][j];
  }
  for (; i < cnt; ++i) {
    int k0 = ek[start + i];
    float v0 = ev[start + i];
#pragma unroll
    for (int g = 0; g < 2; ++g) {
      bf16x8 w0 = *reinterpret_cast<const bf16x8*>(&W2T[(size_t)k0 * NN + c0 + g * 8]);
#pragma unroll
      for (int j = 0; j < 8; ++j) acc[g][j] += v0 * (float)w0[j];
    }
  }
  if (empty[n]) {
#pragma unroll
    for (int g = 0; g < 2; ++g) {
      bf16x8 we = *reinterpret_cast<const bf16x8*>(&W2T[(size_t)n * NN + c0 + g * 8]);
#pragma unroll
      for (int j = 0; j < 8; ++j) acc[g][j] -= (1.0f / NN) * (float)we[j];
    }
  }
#pragma unroll
  for (int g = 0; g < 2; ++g) {
    uint4 o;
    o.x = (uint32_t)f2bf(acc[g][0]) | ((uint32_t)f2bf(acc[g][1]) << 16);
    o.y = (uint32_t)f2bf(acc[g][2]) | ((uint32_t)f2bf(acc[g][3]) << 16);
    o.z = (uint32_t)f2bf(acc[g][4]) | ((uint32_t)f2bf(acc[g][5]) << 16);
    o.w = (uint32_t)f2bf(acc[g][6]) | ((uint32_t)f2bf(acc[g][7]) << 16);
    *reinterpret_cast<uint4*>(&WT[(size_t)n * NN + c0 + g * 8]) = o;
  }
}

// ---------------------------------------------------------------- bf16 bt-GEMM (m97 structure)
// C[row, col] = sum_k A[row, k] * Bt[col, k]; 128x128 tile, 4 waves, BK=32.
__device__ __forceinline__ void gload_lds16(const ushort* g, char* l) {
  __builtin_amdgcn_global_load_lds(
      (__attribute__((address_space(1))) uint32_t*)(uintptr_t)g,
      (__attribute__((address_space(3))) uint32_t*)l, 16, 0, 0);
}

__global__ __launch_bounds__(256)
void gemm_bt_kernel(const ushort* __restrict__ A, const ushort* __restrict__ Bt,
                    float* __restrict__ Cf) {
  __shared__ ushort As[128 * 32];
  __shared__ ushort Bs[128 * 32];
  const int t = threadIdx.x;
  const int wid = t >> 6;
  const int lane = t & 63;
  const int m0 = blockIdx.y * 128;
  const int n0 = blockIdx.x * 128;
  const int wm = wid >> 1, wn = wid & 1;

  f32x4 acc[4][4] = {};

  const ushort* Ag0 = A + (size_t)(m0 + (t >> 2)) * GK + (t & 3) * 8;
  const ushort* Ag1 = Ag0 + (size_t)64 * GK;
  const ushort* Bg0 = Bt + (size_t)(n0 + (t >> 2)) * GK + (t & 3) * 8;
  const ushort* Bg1 = Bg0 + (size_t)64 * GK;
  char* AsW = (char*)As + wid * 1024;
  char* BsW = (char*)Bs + wid * 1024;

  const int fr = lane & 15, fg = lane >> 4;
  const ushort* ArdA = As + (size_t)(wm * 64 + fr) * 32 + fg * 8;
  const ushort* ArdB = Bs + (size_t)(wn * 64 + fr) * 32 + fg * 8;

  for (int kt = 0; kt < GK; kt += 32) {
    gload_lds16(Ag0 + kt, AsW);
    gload_lds16(Ag1 + kt, AsW + 4096);
    gload_lds16(Bg0 + kt, BsW);
    gload_lds16(Bg1 + kt, BsW + 4096);
    __syncthreads();
    bf16x8 af[4], bb[4];
#pragma unroll
    for (int i = 0; i < 4; ++i) af[i] = *reinterpret_cast<const bf16x8*>(ArdA + i * 16 * 32);
#pragma unroll
    for (int i = 0; i < 4; ++i) bb[i] = *reinterpret_cast<const bf16x8*>(ArdB + i * 16 * 32);
#pragma unroll
    for (int i = 0; i < 4; ++i)
#pragma unroll
      for (int j = 0; j < 4; ++j)
        acc[i][j] = __builtin_amdgcn_mfma_f32_16x16x32_bf16(af[i], bb[j], acc[i][j], 0, 0, 0);
    __syncthreads();
  }

  const int cr = lane >> 4, cc = lane & 15;
#pragma unroll
  for (int i = 0; i < 4; ++i)
#pragma unroll
    for (int j = 0; j < 4; ++j)
#pragma unroll
      for (int q = 0; q < 4; ++q) {
        int grow = m0 + wm * 64 + i * 16 + cr * 4 + q;
        int gcol = n0 + wn * 64 + j * 16 + cc;
        Cf[(size_t)grow * GNC + gcol] = acc[i][j][q];
      }
}

// ---------------------------------------------------------------- launch
extern "C" void kernel_launch(void* const* d_in, const int* in_sizes, int n_in,
                              void* d_out, int out_size, void* d_ws, size_t ws_size,
                              hipStream_t stream) {
  const float* x   = (const float*)d_in[0];  // [8,512,2048] -> [4096][2048]
  const float* W1  = (const float*)d_in[1];  // [2048][2048]
  const float* W2  = (const float*)d_in[2];  // [2048][2048]
  const float* e   = (const float*)d_in[3];  // [nnz]
  const int*   eix = (const int*)d_in[4];    // [nnz] sorted flat indices
  const int nnz = in_sizes[3];
  float* out = (float*)d_out;                // [4096][2048] fp32

  // ws layout: 34.39 MB total — byte-identical to the round-3 layout that
  // passed post-timing validation. Do not grow (round-2 lesson).
  char* w = (char*)d_ws;
  ushort* W2T  = (ushort*)w; w += (size_t)NN * NN * 2;    // 8.4 MB  W2^T bf16 [k][p]
  ushort* WT   = (ushort*)w; w += (size_t)NN * NN * 2;    // 8.4 MB  W1^T then Wfused^T [n][p]
  ushort* xb   = (ushort*)w; w += (size_t)4096 * NN * 2;  // 16.8 MB x bf16 [m][p]
  float*  vals = (float*)w;  w += (size_t)nnz * 4;
  int*    ek   = (int*)w;    w += (size_t)nnz * 4;
  float*  ev   = (float*)w;  w += (size_t)nnz * 4;
  int*    hist = (int*)w;    w += NN * 4;
  int*    base = (int*)w;    w += NN * 4;
  int*    curs = (int*)w;    w += NN * 4;
  float*  diag = (float*)w;  w += NN * 4;
  int*    empt = (int*)w;    w += NN * 4;
  float*  uW   = (float*)w;  w += NN * 4;
  int*    ecnt = (int*)w;    w += 256;

  prep_kernel<<<dim3(6145), dim3(256), 0, stream>>>(W1, W2, WT, W2T, x, xb,
                                                    hist, uW, ecnt);
  softmax_hist_kernel<<<dim3(512), dim3(256), 0, stream>>>(eix, e, nnz, vals,
                                                           diag, empt, ecnt, hist);
  scan_uw_kernel<<<dim3(9), dim3(256), 0, stream>>>(hist, base, curs, W2, empt,
                                                    ecnt, uW);
  scatter_kernel<<<dim3((nnz + 255) / 256), dim3(256), 0, stream>>>(eix, vals, nnz,
                                                                    curs, ek, ev);
  spmm_kernel<<<dim3(1024), dim3(256), 0, stream>>>(ek, ev, base, hist, W2T,
                                                    diag, empt, uW, WT);
  gemm_bt_kernel<<<dim3(16, 32), dim3(256), 0, stream>>>(xb, WT, out);
}